// Round 1
// baseline (321.966 us; speedup 1.0000x reference)
//
#include <hip/hip_runtime.h>
#include <math.h>

namespace {
constexpr int   NUM_BINS = 16;
constexpr float TAU      = 0.05f;
constexpr float EPS_SUM  = 1e-8f;
constexpr float EPS_LOG  = 1e-10f;
constexpr int   BLOCK    = 256;
constexpr int   GRID     = 2048;
}

// Kernel 1: per-row work + per-block partial sum of info_gain into d_ws.
__global__ __launch_bounds__(BLOCK) void ev_main(
    const float* __restrict__ obs,          // (8, dim)
    const float* __restrict__ belief,       // (dim, 16)
    float* __restrict__ out_info,           // (dim,)
    float* __restrict__ out_Hprior,         // (dim,)
    float* __restrict__ out_Hpost,          // (dim,)
    float* __restrict__ out_newbelief,      // (dim, 16) -- only 8B aligned!
    float* __restrict__ ws_partials,        // (GRID,)
    int dim)
{
    float local_sum = 0.0f;
    const int stride = BLOCK * GRID;
    for (int r = blockIdx.x * BLOCK + threadIdx.x; r < dim; r += stride) {
        // ---- load belief row (16B-aligned input buffer) ----
        float c[NUM_BINS];
        const float4* bp = reinterpret_cast<const float4*>(belief) + (size_t)r * 4;
        float4 v0 = bp[0];
        float4 v1 = bp[1];
        float4 v2 = bp[2];
        float4 v3 = bp[3];
        c[0]=v0.x;  c[1]=v0.y;  c[2]=v0.z;  c[3]=v0.w;
        c[4]=v1.x;  c[5]=v1.y;  c[6]=v1.z;  c[7]=v1.w;
        c[8]=v2.x;  c[9]=v2.y;  c[10]=v2.z; c[11]=v2.w;
        c[12]=v3.x; c[13]=v3.y; c[14]=v3.z; c[15]=v3.w;

        float s = 0.0f;
#pragma unroll
        for (int j = 0; j < NUM_BINS; ++j) s += c[j];

        // ---- observation mean over the 8 rows (coalesced per k) ----
        float om = 0.0f;
#pragma unroll
        for (int k = 0; k < 8; ++k) om += obs[(size_t)k * dim + r];
        om *= 0.125f;

        // sigmoid -> bin (precise expf: bin boundaries must match reference)
        float sig = 1.0f / (1.0f + expf(-om));
        int bin = (int)(sig * 15.0f);
        bin = bin < 0 ? 0 : (bin > 15 ? 15 : bin);

        float inv_prior = 1.0f / fmaxf(s, EPS_SUM);
        float inv_post  = 1.0f / fmaxf(s + 1.0f, EPS_SUM);

        float Hpr = 0.0f, Hpo = 0.0f, ig = 0.0f;
        float nb[NUM_BINS];
#pragma unroll
        for (int j = 0; j < NUM_BINS; ++j) {
            float cj = c[j];
            float oh = (j == bin) ? 1.0f : 0.0f;
            float p  = cj * inv_prior;
            float pp = (cj + oh) * inv_post;
            float lp  = log2f(p  + EPS_LOG);
            float lpp = log2f(pp + EPS_LOG);
            Hpr -= p  * lp;
            Hpo -= pp * lpp;
            ig  += pp * (lpp - lp);           // == pp * log2((pp+e)/(p+e))
            nb[j] = fmaxf(cj * (1.0f - TAU) + oh * TAU, 0.01f);
        }
        ig = fmaxf(ig, 0.0f);
        local_sum += ig;

        out_info[r]   = ig;
        out_Hprior[r] = Hpr;
        out_Hpost[r]  = Hpo;

        // new_belief slice starts at float offset 3*dim+2 -> 8B aligned only.
        float2* nbp = reinterpret_cast<float2*>(out_newbelief) + (size_t)r * 8;
#pragma unroll
        for (int j = 0; j < 8; ++j)
            nbp[j] = make_float2(nb[2*j], nb[2*j + 1]);
    }

    // ---- block reduction of info_gain partials ----
    __shared__ float sdata[BLOCK];
    sdata[threadIdx.x] = local_sum;
    __syncthreads();
#pragma unroll
    for (int off = BLOCK / 2; off > 0; off >>= 1) {
        if (threadIdx.x < off) sdata[threadIdx.x] += sdata[threadIdx.x + off];
        __syncthreads();
    }
    if (threadIdx.x == 0) ws_partials[blockIdx.x] = sdata[0];
}

// Kernel 2: reduce GRID partials -> mean_info_gain + epistemic_value scalars.
__global__ __launch_bounds__(BLOCK) void ev_finalize(
    const float* __restrict__ ws_partials,
    float* __restrict__ out_mean,
    float* __restrict__ out_epi,
    int n_partials, float inv_dim)
{
    float s = 0.0f;
    for (int i = threadIdx.x; i < n_partials; i += BLOCK) s += ws_partials[i];
    __shared__ float sdata[BLOCK];
    sdata[threadIdx.x] = s;
    __syncthreads();
#pragma unroll
    for (int off = BLOCK / 2; off > 0; off >>= 1) {
        if (threadIdx.x < off) sdata[threadIdx.x] += sdata[threadIdx.x + off];
        __syncthreads();
    }
    if (threadIdx.x == 0) {
        float mean = sdata[0] * inv_dim;
        *out_mean = mean;
        *out_epi  = 1.0f / (1.0f + expf(-(mean * 50.0f - 1.0f)));
    }
}

extern "C" void kernel_launch(void* const* d_in, const int* in_sizes, int n_in,
                              void* d_out, int out_size, void* d_ws, size_t ws_size,
                              hipStream_t stream)
{
    const float* obs    = (const float*)d_in[0];   // (8, dim) fp32
    const float* belief = (const float*)d_in[1];   // (dim, 16) fp32
    const int dim = in_sizes[0] / 8;

    // Output layout (flat, return order):
    // [0, dim)              info_gain
    // [dim]                 mean_info_gain
    // [dim+1, 2*dim+1)      H_prior
    // [2*dim+1, 3*dim+1)    H_posterior
    // [3*dim+1]             epistemic_value
    // [3*dim+2, 3*dim+2+16*dim)  new_belief_counts
    float* o             = (float*)d_out;
    float* out_info      = o;
    float* out_mean      = o + dim;
    float* out_Hprior    = o + dim + 1;
    float* out_Hpost     = o + 2 * (size_t)dim + 1;
    float* out_epi       = o + 3 * (size_t)dim + 1;
    float* out_newbelief = o + 3 * (size_t)dim + 2;

    float* partials = (float*)d_ws;   // GRID floats; fully overwritten each call

    ev_main<<<GRID, BLOCK, 0, stream>>>(obs, belief, out_info, out_Hprior,
                                        out_Hpost, out_newbelief, partials, dim);
    ev_finalize<<<1, BLOCK, 0, stream>>>(partials, out_mean, out_epi, GRID,
                                         1.0f / (float)dim);
}

// Round 2
// 316.594 us; speedup vs baseline: 1.0170x; 1.0170x over previous
//
#include <hip/hip_runtime.h>
#include <math.h>

namespace {
constexpr int   NUM_BINS = 16;
constexpr float TAU      = 0.05f;
constexpr float EPS_SUM  = 1e-8f;
constexpr float EPS_LOG  = 1e-10f;
constexpr int   BLOCK    = 256;
constexpr int   GRID     = 2048;
}

// Sum x across the 4 lanes of a quad via DPP quad_perm (VALU pipe, no LDS).
// quad_perm ctrl: 0xB1 = (1,0,3,2) = xor 1 ; 0x4E = (2,3,0,1) = xor 2.
__device__ inline float quad_sum(float x) {
    int a = __builtin_amdgcn_mov_dpp(__float_as_int(x), 0xB1, 0xF, 0xF, true);
    x += __int_as_float(a);
    a = __builtin_amdgcn_mov_dpp(__float_as_int(x), 0x4E, 0xF, 0xF, true);
    x += __int_as_float(a);
    return x;
}

// Kernel 1: 4 lanes cooperate on one belief row. All global accesses are
// lane-linear (fully coalesced): belief float4/lane, nb 2x float2/lane.
__global__ __launch_bounds__(BLOCK) void ev_main(
    const float* __restrict__ obs,          // (8, dim)
    const float* __restrict__ belief,       // (dim, 16)
    float* __restrict__ out_info,           // (dim,)
    float* __restrict__ out_Hprior,         // (dim,)
    float* __restrict__ out_Hpost,          // (dim,)
    float* __restrict__ out_newbelief,      // (dim,16) slice, 8B-aligned only
    float* __restrict__ ws_partials,        // (GRID,)
    int dim)
{
    const int tid    = blockIdx.x * BLOCK + threadIdx.x;
    const int stride = BLOCK * GRID;
    const int W      = dim * 4;             // total quarter-row work items
    float local_sum = 0.0f;                 // accumulates 4x ig per row

    const float4* belief4 = reinterpret_cast<const float4*>(belief);
    float2* nb2 = reinterpret_cast<float2*>(out_newbelief);

#pragma unroll 2
    for (int f = tid; f < W; f += stride) {
        const int r = f >> 2;               // row (uniform within quad)
        const int m = f & 3;                // lane's chunk within row

        // ---- coalesced loads ----
        float4 c4 = belief4[f];             // 16B/lane, lane-linear
        float cs = (c4.x + c4.y) + (c4.z + c4.w);
        // each lane reads 2 of the 8 observation rows for this column
        float os = obs[(size_t)(2 * m) * dim + r]
                 + obs[(size_t)(2 * m + 1) * dim + r];

        // ---- quad reductions (DPP, VALU pipe) ----
        cs = quad_sum(cs);                  // row count-sum
        os = quad_sum(os);                  // sum of 8 obs values
        float om = os * 0.125f;

        float sig = 1.0f / (1.0f + expf(-om));
        int bin = (int)(sig * 15.0f);
        bin = bin < 0 ? 0 : (bin > 15 ? 15 : bin);

        float inv_prior = 1.0f / fmaxf(cs, EPS_SUM);
        float inv_post  = 1.0f / fmaxf(cs + 1.0f, EPS_SUM);

        float Hpr = 0.0f, Hpo = 0.0f, ig = 0.0f;
        float cc[4] = {c4.x, c4.y, c4.z, c4.w};
        float nb[4];
        const int j0 = m * 4;
#pragma unroll
        for (int e = 0; e < 4; ++e) {
            float cj = cc[e];
            float oh = (j0 + e == bin) ? 1.0f : 0.0f;
            float p  = cj * inv_prior;
            float pp = (cj + oh) * inv_post;
            float lp  = log2f(p  + EPS_LOG);
            float lpp = log2f(pp + EPS_LOG);
            Hpr -= p  * lp;
            Hpo -= pp * lpp;
            ig  += pp * (lpp - lp);
            nb[e] = fmaxf(cj * (1.0f - TAU) + oh * TAU, 0.01f);
        }
        Hpr = quad_sum(Hpr);
        Hpo = quad_sum(Hpo);
        ig  = fmaxf(quad_sum(ig), 0.0f);
        local_sum += ig;                    // counted 4x; divided out later

        if (m == 0) {
            out_info[r]   = ig;
            out_Hprior[r] = Hpr;
            out_Hpost[r]  = Hpo;
        }

        // ---- coalesced nb store (8B-aligned output slice -> float2) ----
        nb2[(size_t)f * 2]     = make_float2(nb[0], nb[1]);
        nb2[(size_t)f * 2 + 1] = make_float2(nb[2], nb[3]);
    }

    // ---- block reduction of info_gain partials ----
    __shared__ float sdata[BLOCK];
    sdata[threadIdx.x] = local_sum;
    __syncthreads();
#pragma unroll
    for (int off = BLOCK / 2; off > 0; off >>= 1) {
        if (threadIdx.x < off) sdata[threadIdx.x] += sdata[threadIdx.x + off];
        __syncthreads();
    }
    if (threadIdx.x == 0) ws_partials[blockIdx.x] = sdata[0];
}

// Kernel 2: reduce GRID partials -> mean_info_gain + epistemic_value.
__global__ __launch_bounds__(BLOCK) void ev_finalize(
    const float* __restrict__ ws_partials,
    float* __restrict__ out_mean,
    float* __restrict__ out_epi,
    int n_partials, float inv_cnt)
{
    float s = 0.0f;
    for (int i = threadIdx.x; i < n_partials; i += BLOCK) s += ws_partials[i];
    __shared__ float sdata[BLOCK];
    sdata[threadIdx.x] = s;
    __syncthreads();
#pragma unroll
    for (int off = BLOCK / 2; off > 0; off >>= 1) {
        if (threadIdx.x < off) sdata[threadIdx.x] += sdata[threadIdx.x + off];
        __syncthreads();
    }
    if (threadIdx.x == 0) {
        float mean = sdata[0] * inv_cnt;
        *out_mean = mean;
        *out_epi  = 1.0f / (1.0f + expf(-(mean * 50.0f - 1.0f)));
    }
}

extern "C" void kernel_launch(void* const* d_in, const int* in_sizes, int n_in,
                              void* d_out, int out_size, void* d_ws, size_t ws_size,
                              hipStream_t stream)
{
    const float* obs    = (const float*)d_in[0];   // (8, dim) fp32
    const float* belief = (const float*)d_in[1];   // (dim, 16) fp32
    const int dim = in_sizes[0] / 8;

    // Output layout (flat, return order):
    // [0, dim) info | [dim] mean | [dim+1, 2dim+1) H_prior |
    // [2dim+1, 3dim+1) H_post | [3dim+1] epi | [3dim+2, ...) new_belief
    float* o             = (float*)d_out;
    float* out_info      = o;
    float* out_mean      = o + dim;
    float* out_Hprior    = o + dim + 1;
    float* out_Hpost     = o + 2 * (size_t)dim + 1;
    float* out_epi       = o + 3 * (size_t)dim + 1;
    float* out_newbelief = o + 3 * (size_t)dim + 2;

    float* partials = (float*)d_ws;   // GRID floats; fully overwritten each call

    ev_main<<<GRID, BLOCK, 0, stream>>>(obs, belief, out_info, out_Hprior,
                                        out_Hpost, out_newbelief, partials, dim);
    // local_sum counted each row 4x (once per quad lane) -> divide by 4*dim
    ev_finalize<<<1, BLOCK, 0, stream>>>(partials, out_mean, out_epi, GRID,
                                         1.0f / (4.0f * (float)dim));
}